// Round 17
// baseline (161.859 us; speedup 1.0000x reference)
//
#include <hip/hip_runtime.h>
#include <hip/hip_bf16.h>

#define B_ 4
#define C_ 32
#define H_ 256
#define W_ 256
#define S_ 65536      // H*W
#define NP_ 9
#define OC_ 288       // C_*NP_
#define PR 258        // padded rows
#define PWN 264       // padded width stride (NHWC)
#define XGUARD 260    // guard pixels on each side of xb16
#define XSTRIDE 66056 // per-batch px stride of xb16 (260+65536+260)

using bf16 = __hip_bfloat16;
typedef __attribute__((ext_vector_type(8)))  short  short8;
typedef __attribute__((ext_vector_type(4)))  short  short4_t;
typedef __attribute__((ext_vector_type(2)))  short  short2_t;
typedef __attribute__((ext_vector_type(16))) float  f32x16;

__device__ __forceinline__ float b2f(short s) {
    return __uint_as_float(((unsigned)(unsigned short)s) << 16);
}

// ---------------- prep bodies ----------------
template<int IC, int OC>
__device__ __forceinline__ void prepA_body(int fid, const float* __restrict__ w,
                                           bf16* __restrict__ apk)
{
    constexpr int NK = 9 * IC / 16;
    int tile = fid >> 9;
    int l = (fid >> 3) & 63;
    int j = fid & 7;
    int mt = tile / NK;
    int ks = tile - mt * NK;
    int q = l >> 5;
    int oc = mt * 32 + (l & 31);
    int k = ks * 16 + q * 8 + j;
    int tap = k / IC;
    int ic = k - tap * IC;
    apk[fid] = __float2bfloat16(w[((oc * IC + ic) * 3 + tap / 3) * 3 + tap % 3]);
}

template<int G>
__device__ __forceinline__ void zerob_body(int b, int p, uint4* __restrict__ buf)
{
    int gran;
    if (p < 2 * PWN * G) {
        int row = (p < PWN * G) ? 0 : 257;
        int rem = p % (PWN * G);
        gran = row * PWN * G + rem;
    } else {
        int p2 = p - 2 * PWN * G;
        int col = (p2 < 256 * G) ? 0 : 257;
        int rem = p2 % (256 * G);
        int r = rem / G + 1;
        int icg = rem - (rem / G) * G;
        gran = (r * PWN + col) * G + icg;
    }
    buf[(size_t)b * PR * PWN * G + gran] = uint4{0, 0, 0, 0};
}

__device__ __forceinline__ void prep_body(
    int idx,
    const float* __restrict__ wk, const float* __restrict__ wv,
    const float* __restrict__ wq,
    const float* __restrict__ w1, const float* __restrict__ w2,
    const float* __restrict__ w3,
    bf16* __restrict__ apk0, bf16* __restrict__ apk1,
    bf16* __restrict__ apk2, bf16* __restrict__ apk3,
    uint4* __restrict__ tA, uint4* __restrict__ t1, uint4* __restrict__ t2,
    uint4* __restrict__ xb16)
{
    if (idx < 19456) {
        int j    = idx & 7;
        int lane = (idx >> 3) & 63;
        int ks   = (idx >> 9) & 1;
        int mt   = idx >> 10;
        int oc = lane & 31;
        int ic = ks * 16 + (lane >> 5) * 8 + j;
        const float* w; int ocg;
        if (mt < 9)       { w = wk; ocg = mt * 32 + oc; }
        else if (mt < 18) { w = wv; ocg = (mt - 9) * 32 + oc; }
        else              { w = wq; ocg = oc; }
        apk0[idx] = __float2bfloat16(w[ocg * C_ + ic]);
    } else if (idx < 28672) {
        prepA_body<32, 32>(idx - 19456, w1, apk1);
    } else if (idx < 47104) {
        prepA_body<32, 64>(idx - 28672, w2, apk2);
    } else if (idx < 65536) {
        prepA_body<64, 32>(idx - 47104, w3, apk3);
    } else if (idx < 82176) {
        int i5 = idx - 65536;
        zerob_body<4>(i5 / 4160, i5 % 4160, tA);
    } else if (idx < 98816) {
        int i6 = idx - 82176;
        zerob_body<4>(i6 / 4160, i6 % 4160, t1);
    } else if (idx < 132096) {
        int i7 = idx - 98816;
        zerob_body<8>(i7 / 8320, i7 % 8320, t2);
    } else if (idx < 142464) {
        // zero xb16 guard bands: head [-260,0), tail [65536,65796) per batch + slack
        int i8 = idx - 132096;           // [0, 10368)
        size_t off;
        if (i8 < 8320) {
            int b = i8 / 2080, r = i8 - b * 2080;
            if (r < 1040) off = (size_t)b * (XSTRIDE * 4) + r;
            else          off = ((size_t)b * XSTRIDE + XGUARD + 65536) * 4 + (r - 1040);
        } else {
            off = (size_t)(4 * XSTRIDE) * 4 + (i8 - 8320);
        }
        xb16[off] = uint4{0, 0, 0, 0};
    }
}

// ---------------- K_qp: merged {k_prep} + {1x1 Q-conv + x->bf16 NHWC repack} -------
__global__ __launch_bounds__(256) void k_qp(
    const float* __restrict__ x,
    const float* __restrict__ wk, const float* __restrict__ wv,
    const float* __restrict__ wq, const float* __restrict__ bq,
    const float* __restrict__ w1, const float* __restrict__ w2,
    const float* __restrict__ w3,
    bf16* __restrict__ apk0, bf16* __restrict__ apk1,
    bf16* __restrict__ apk2, bf16* __restrict__ apk3,
    uint4* __restrict__ tA, uint4* __restrict__ t1, uint4* __restrict__ t2,
    bf16* __restrict__ xqs, bf16* __restrict__ xb16)
{
    __shared__ bf16 lbuf[32][140];
    int tid = threadIdx.x;

    if (blockIdx.x >= 2048) {
        prep_body((blockIdx.x - 2048) * 256 + tid, wk, wv, wq, w1, w2, w3,
                  apk0, apk1, apk2, apk3, tA, t1, t2, (uint4*)xb16);
        return;
    }

    int bh  = blockIdx.x >> 9;          // batch 0..3
    int blk = blockIdx.x & 511;
    int pixw0 = blk << 7;
    int wvi  = tid >> 6;
    int lane = tid & 63;
    int col  = lane & 31, q = lane >> 5;
    int pix  = pixw0 + wvi * 32 + col;

    const float* xb = x + (size_t)bh * (C_ * S_);

    short8 bfrag[2];
#pragma unroll
    for (int kk = 0; kk < 2; ++kk)
#pragma unroll
        for (int j = 0; j < 8; ++j) {
            bf16 h = __float2bfloat16(xb[(size_t)(kk * 16 + q * 8 + j) * S_ + pix]);
            bfrag[kk][j] = *reinterpret_cast<short*>(&h);
        }

    // x -> bf16 NHWC: granule g = ic/8 = kk*2+q
    {
        bf16* xr = xb16 + ((size_t)bh * XSTRIDE + XGUARD + pix) * 32;
        *reinterpret_cast<short8*>(xr + (q << 3))       = bfrag[0];
        *reinterpret_cast<short8*>(xr + ((2 + q) << 3)) = bfrag[1];
    }

    // self-packed q-weight fragments (same layout k_prep would emit for mt=18)
    short8 wfrag[2];
#pragma unroll
    for (int kk = 0; kk < 2; ++kk)
#pragma unroll
        for (int j = 0; j < 8; ++j) {
            bf16 h = __float2bfloat16(wq[col * C_ + kk * 16 + q * 8 + j]);
            wfrag[kk][j] = *reinterpret_cast<short*>(&h);
        }

    f32x16 acc = {};
    acc = __builtin_amdgcn_mfma_f32_32x32x16_bf16(bfrag[0], wfrag[0], acc, 0, 0, 0);
    acc = __builtin_amdgcn_mfma_f32_32x32x16_bf16(bfrag[1], wfrag[1], acc, 0, 0, 0);
    float bbv = bq[col];
#pragma unroll
    for (int g4 = 0; g4 < 4; ++g4) {
        short4_t sv;
#pragma unroll
        for (int j = 0; j < 4; ++j) {
            bf16 hb = __float2bfloat16(acc[g4 * 4 + j] + bbv);
            sv[j] = *reinterpret_cast<short*>(&hb);
        }
        *reinterpret_cast<short4_t*>(&lbuf[col][wvi * 32 + 8 * g4 + 4 * q]) = sv;
    }
    __syncthreads();
    // swizzled q store: row (ch*2048 + tb) holds px [tb*32, tb*32+32) of plane ch
    int ch0 = tid >> 4, chk = tid & 15, ch1 = ch0 + 16;
    short8 v0 = *reinterpret_cast<const short8*>(&lbuf[ch0][chk * 8]);
    short8 v1 = *reinterpret_cast<const short8*>(&lbuf[ch1][chk * 8]);
    int tb = (pixw0 >> 5) + (chk >> 2);
    int G2 = chk & 3;
    bf16* qb = xqs + (size_t)bh * (32 * S_);
    short4_t lo0 = {v0[0], v0[1], v0[2], v0[3]}, hi0 = {v0[4], v0[5], v0[6], v0[7]};
    short4_t lo1 = {v1[0], v1[1], v1[2], v1[3]}, hi1 = {v1[4], v1[5], v1[6], v1[7]};
    *reinterpret_cast<short4_t*>(qb + (ch0 * 2048 + tb) * 32 + G2 * 4)      = lo0;
    *reinterpret_cast<short4_t*>(qb + (ch0 * 2048 + tb) * 32 + 16 + G2 * 4) = hi0;
    *reinterpret_cast<short4_t*>(qb + (ch1 * 2048 + tb) * 32 + G2 * 4)      = lo1;
    *reinterpret_cast<short4_t*>(qb + (ch1 * 2048 + tb) * 32 + 16 + G2 * 4) = hi1;
}

// ---------------- fused K/V-conv + attention (ping-pong + x/q double prefetch) -----
// Block = (batch, 512-px chunk), 1024 threads, 111KB dyn LDS, 1 block/CU.
// Both q AND x fragments for tap p+1 are register-prefetched before tap p's
// barrier, so all global latency flies under P2 + barrier. 1 barrier/tap.

#define Q_LOAD(T, PN, QA, QB)                                                         \
{                                                                                     \
    int Tg = tgbase + (T);                                                            \
    if (Tg < 2048) {                                                                  \
        int plane_base_n = (((PN) << 5) + col) << 16;                                 \
        unsigned n = (unsigned)plane_base_n + ((unsigned)Tg << 5);                    \
        unsigned tl = n / 288u;                                                       \
        const bf16* qp = xqb + ((size_t)tl << 5) + (q << 4);                          \
        QA = *reinterpret_cast<const short8*>(qp);                                    \
        QB = *reinterpret_cast<const short8*>(qp + 8);                                \
    }                                                                                 \
}

#define X_LOAD(T, PN, XA, XB)                                                         \
{                                                                                     \
    int Tg = tgbase + (T);                                                            \
    if (Tg < 2048) {                                                                  \
        int din = (PN) / 3 - 1, djn = (PN) - ((PN) / 3) * 3 - 1;                      \
        int shfn = din * 256 + djn;                                                   \
        const bf16* xp = xbb + (size_t)(XGUARD + (Tg << 5) + shfn + col) * 32;        \
        XA = *reinterpret_cast<const short8*>(xp + (q << 3));                         \
        XB = *reinterpret_cast<const short8*>(xp + ((2 + q) << 3));                   \
    }                                                                                 \
}

#define DO_TILE(T, SQ, QAv, QBv, XAv, XBv, PP)                                        \
{                                                                                     \
    int Tg = tgbase + (T);                                                            \
    if (Tg < 2048) {                                                                  \
        short8 qA = QAv;                                                              \
        short8 qB = QBv;                                                              \
        bool hbad  = ((((T) << 5) < hb_lo) || (((T) << 5) >= hb_hi));                 \
        bool tb_lo = (dj == -1) && ((Tg & 7) == 0);                                   \
        bool tb_hi = (dj == 1) && ((Tg & 7) == 7);                                    \
        if (tb_lo && q == 0) qA[0] = 0;                                               \
        if (tb_hi && q == 1) qB[7] = 0;                                               \
        f32x16 ka = {bK, bK, bK, bK, bK, bK, bK, bK, bK, bK, bK, bK, bK, bK, bK, bK}; \
        __builtin_amdgcn_s_setprio(1);                                                \
        ka = __builtin_amdgcn_mfma_f32_32x32x16_bf16(XAv, apkv[((PP) * 2 + 0) * 64 + lane], ka, 0, 0, 0); \
        ka = __builtin_amdgcn_mfma_f32_32x32x16_bf16(XBv, apkv[((PP) * 2 + 1) * 64 + lane], ka, 0, 0, 0); \
        __builtin_amdgcn_s_setprio(0);                                                \
        float dot = 0.f;                                                              \
        _Pragma("unroll")                                                             \
        for (int j3 = 0; j3 < 4; ++j3) {                                              \
            dot += ka[j3]      * b2f(qA[j3]);                                         \
            dot += ka[4 + j3]  * b2f(qA[4 + j3]);                                     \
            dot += ka[8 + j3]  * b2f(qB[j3]);                                         \
            dot += ka[12 + j3] * b2f(qB[4 + j3]);                                     \
        }                                                                             \
        if (hbad) dot = 0.f;                                                          \
        dot += __shfl_xor(dot, 32);                                                   \
        if (q == (SQ)) scW[(T) * 32 + col] = dot;                                     \
        f32x16 vh = {bV, bV, bV, bV, bV, bV, bV, bV, bV, bV, bV, bV, bV, bV, bV, bV}; \
        __builtin_amdgcn_s_setprio(1);                                                \
        vh = __builtin_amdgcn_mfma_f32_32x32x16_bf16(XAv, apkv[((9 + (PP)) * 2 + 0) * 64 + lane], vh, 0, 0, 0); \
        vh = __builtin_amdgcn_mfma_f32_32x32x16_bf16(XBv, apkv[((9 + (PP)) * 2 + 1) * 64 + lane], vh, 0, 0, 0); \
        __builtin_amdgcn_s_setprio(0);                                                \
        _Pragma("unroll")                                                             \
        for (int G2 = 0; G2 < 4; ++G2) {                                              \
            short4_t sv;                                                              \
            _Pragma("unroll")                                                         \
            for (int j3 = 0; j3 < 4; ++j3) {                                          \
                float val = hbad ? 0.f : vh[G2 * 4 + j3];                             \
                bf16 hcv = __float2bfloat16(val);                                     \
                sv[j3] = *reinterpret_cast<short*>(&hcv);                             \
            }                                                                         \
            if (G2 == 0 && tb_lo && q == 0) sv[0] = 0;                                \
            if (G2 == 3 && tb_hi && q == 1) sv[3] = 0;                                \
            *reinterpret_cast<short4_t*>(kvW + col * 1616 +                           \
                ((((T) << 2) + (G2 ^ xcol)) << 4) + q * 8) = sv;                      \
        }                                                                             \
    }                                                                                 \
}

#define P1_SETUP(PP)                                                                  \
    int dj = (PP) - ((PP) / 3) * 3 - 1;                                               \
    int di = (PP) / 3 - 1;                                                            \
    int hb_lo = (di == -1) ? (256 - s0) : (-0x40000000);                              \
    int hb_hi = (di == 1) ? (65280 - s0) : 0x40000000;                                \
    float bK = bk[(PP) * 32 + col];                                                   \
    float bV = bv[(PP) * 32 + col];

__global__ __launch_bounds__(1024, 4) void k_fused(
    const bf16* __restrict__ xb16,      // [4][XSTRIDE][32] bf16 NHWC (+guards)
    const bf16* __restrict__ apk,       // packed weights [19][2][64][8]
    const float* __restrict__ bk, const float* __restrict__ bv,
    const bf16* __restrict__ xqs,       // [4][65536 rows][32] swizzled rows
    bf16* __restrict__ att)             // [4][2097152] flat bf16
{
    extern __shared__ char smem_raw[];
    char*  kvB0 = smem_raw;                                     // 51712
    char*  kvB1 = smem_raw + 51712;                             // 51712
    float* scL0 = reinterpret_cast<float*>(smem_raw + 103424);  // 3200
    float* scL1 = reinterpret_cast<float*>(smem_raw + 106624);  // 3200
    unsigned short* scM = reinterpret_cast<unsigned short*>(smem_raw + 109824); // 1152
    // total 110,976

    int bb = blockIdx.x >> 7;
    int s0 = (blockIdx.x & 127) << 9;
    int tgbase = s0 >> 5;

    int tid  = threadIdx.x;
    int lane = tid & 63;
    int wv   = tid >> 6;                // 0..15
    int col  = lane & 31;
    int q    = lane >> 5;
    int xcol = (col >> 3) & 3;

    size_t qbase = ((size_t)bb << 21);
    const bf16* xqb = xqs + qbase;
    const bf16* xbb = xb16 + (size_t)bb * XSTRIDE * 32;
    const short8* apkv = reinterpret_cast<const short8*>(apk);

    // ---- strip validity + seg-mask table (once per block) ----
    if (tid < 576) {
        int krow = tid >= 288;
        int i2 = tid - (krow ? 288 : 0);
        int pp = i2 >> 5, dpc = i2 & 31;
        int plane_base_r = ((pp << 5) + dpc) << 16;
        unsigned tl = ((unsigned)(plane_base_r + s0 + 287)) / 288u + (unsigned)krow;
        int sk0 = (int)(tl * 288u) - plane_base_r;
        unsigned m = 0;
        if (sk0 < s0 + 512 && sk0 <= 65248) {
            m = 0x8000u;
#pragma unroll
            for (int seg = 0; seg < 9; ++seg) {
                int rm = (int)tl * 9 + seg;
                int pm = rm >> 16, sm = rm & 65535;
                int dim = pm / 3 - 1, djm = pm - (pm / 3) * 3 - 1;
                int hm = sm >> 8, wm = sm & 255;
                bool mval = ((unsigned)(hm + dim) < 256u) && ((unsigned)(wm + djm) < 256u);
                m |= (mval ? 1u : 0u) << seg;
            }
        }
        scM[tid] = (unsigned short)m;
    }

    // prologue: x+q for tap 0, P1(0) into buf0, prefetch x+q for tap 1
    short8 qA0, qB0, qA1, qB1, xA0, xB0, xA1, xB1;
    Q_LOAD(wv, 0, qA0, qB0)
    X_LOAD(wv, 0, xA0, xB0)
    if (wv < 9) { Q_LOAD(wv + 16, 0, qA1, qB1) X_LOAD(wv + 16, 0, xA1, xB1) }
    {
        P1_SETUP(0)
        char*  kvW = kvB0;
        float* scW = scL0;
        DO_TILE(wv, 0, qA0, qB0, xA0, xB0, 0)
        if (wv < 9) { DO_TILE(wv + 16, 1, qA1, qB1, xA1, xB1, 0) }
        Q_LOAD(wv, 1, qA0, qB0)
        X_LOAD(wv, 1, xA0, xB0)
        if (wv < 9) { Q_LOAD(wv + 16, 1, qA1, qB1) X_LOAD(wv + 16, 1, xA1, xB1) }
    }
    __syncthreads();

    // P2 thread map: tid<512, 8 threads per (plane, krow)
    int grp  = tid >> 3, sub = tid & 7;
    int dp   = grp & 31;
    int krow = (grp >> 5) & 1;
    int hh   = sub >> 1;
    int sh   = sub & 1;
    bool athr = tid < 512;
    int swz = (dp >> 3) & 3;

#pragma unroll 1
    for (int p = 0; p < 9; ++p) {
        const char*  kvR = (p & 1) ? kvB1 : kvB0;
        const float* scR = (p & 1) ? scL1 : scL0;

        // ---- P2(p): softmax from scR/scM + PV from kvR ----
        if (athr) {
            unsigned mflags = scM[krow * 288 + p * 32 + dp];
            if (mflags & 0x8000u) {
                int plane_base_r = ((p << 5) + dp) << 16;
                unsigned tl = ((unsigned)(plane_base_r + s0 + 287)) / 288u + (unsigned)krow;
                int sk0 = (int)(tl * 288u) - plane_base_r;
                int t0 = (sk0 - s0) >> 5;
                float sc[9];
#pragma unroll
                for (int seg = 0; seg < 9; ++seg)
                    sc[seg] = ((mflags >> seg) & 1u) ? scR[(t0 + seg) * 32 + dp] * 0.125f : 0.f;
                float mx = sc[0];
#pragma unroll
                for (int s2 = 1; s2 < 9; ++s2) mx = fmaxf(mx, sc[s2]);
                float wgt[9];
                float sum = 0.f;
#pragma unroll
                for (int s2 = 0; s2 < 9; ++s2) { wgt[s2] = __expf(sc[s2] - mx); sum += wgt[s2]; }
                float inv_ = 1.f / sum;

                float oacc[4] = {0.f, 0.f, 0.f, 0.f};
#pragma unroll
                for (int seg = 0; seg < 9; ++seg) {
                    short4_t vg = *reinterpret_cast<const short4_t*>(
                        kvR + dp * 1616 + ((((t0 + seg) << 2) + (hh ^ swz)) << 4) + sh * 8);
                    float w_ = wgt[seg];
#pragma unroll
                    for (int j = 0; j < 4; ++j) oacc[j] += w_ * b2f(vg[j]);
                }
                short4_t sv;
#pragma unroll
                for (int j = 0; j < 4; ++j) {
                    bf16 h = __float2bfloat16(oacc[j] * inv_);
                    sv[j] = *reinterpret_cast<short*>(&h);
                }
                *reinterpret_cast<short4_t*>(att + qbase + ((size_t)tl << 5) + hh * 8 + sh * 4) = sv;
            }
        }

        // ---- P1(p+1): conv into the other buffer (prefetched x+q regs) ----
        if (p < 8) {
            P1_SETUP(p + 1)
            char*  kvW = ((p + 1) & 1) ? kvB1 : kvB0;
            float* scW = ((p + 1) & 1) ? scL1 : scL0;
            DO_TILE(wv, 0, qA0, qB0, xA0, xB0, p + 1)
            if (wv < 9) { DO_TILE(wv + 16, 1, qA1, qB1, xA1, xB1, p + 1) }
            if (p < 7) {
                Q_LOAD(wv, p + 2, qA0, qB0)
                X_LOAD(wv, p + 2, xA0, xB0)
                if (wv < 9) { Q_LOAD(wv + 16, p + 2, qA1, qB1) X_LOAD(wv + 16, p + 2, xA1, xB1) }
            }
        }
        __syncthreads();
    }
}

// ---------------- straddler rows: strip crosses a plane boundary ------------------
__global__ __launch_bounds__(320) void k_strad(
    const bf16* __restrict__ xb16,
    const float* __restrict__ wk, const float* __restrict__ bk,
    const float* __restrict__ wv, const float* __restrict__ bv,
    const bf16* __restrict__ xqs, bf16* __restrict__ att)
{
    __shared__ float kL[288], vL[288], qL[32], wgtL[10];
    int e = blockIdx.x;
    int b = e >> 8, i = e & 255;
    int g = i >> 3, u = i & 7;
    int tl = g * 2048 + (((2040 + u) * 1593) & 2047);
    int tid = threadIdx.x;

    if (tid < 288) {
        int f  = tl * 288 + tid;
        int cp = f >> 16;
        int sp = f & 65535;
        int tap = cp >> 5;
        int di = tap / 3 - 1, dj = tap - (tap / 3) * 3 - 1;
        int h = sp >> 8, w = sp & 255;
        bool valid = ((unsigned)(h + di) < 256u) && ((unsigned)(w + dj) < 256u);
        float kv_ = 0.f, vv_ = 0.f;
        if (valid) {
            int sx = sp + di * 256 + dj;
            const bf16* xp = xb16 + ((size_t)b * XSTRIDE + XGUARD + sx) * 32;
            const float* wkp = wk + cp * 32;
            const float* wvp = wv + cp * 32;
            float ks = bk[cp], vs = bv[cp];
            short8 xg[4];
#pragma unroll
            for (int gg = 0; gg < 4; ++gg)
                xg[gg] = *reinterpret_cast<const short8*>(xp + gg * 8);
#pragma unroll
            for (int gg = 0; gg < 4; ++gg)
#pragma unroll
                for (int j = 0; j < 8; ++j) {
                    float xv_ = b2f(xg[gg][j]);
                    ks += wkp[gg * 8 + j] * xv_;
                    vs += wvp[gg * 8 + j] * xv_;
                }
            kv_ = ks; vv_ = vs;
        }
        kL[tid] = kv_; vL[tid] = vv_;
    }
    if (tid < 32) {
        // q-row tl element u=tid at swizzled pos(u)
        int pos = ((tid >> 2) & 1) * 16 + (tid >> 3) * 4 + (tid & 3);
        bf16 hv = xqs[(size_t)b * (32 * S_) + (size_t)tl * 32 + pos];
        qL[tid] = b2f(*reinterpret_cast<short*>(&hv));
    }
    __syncthreads();
    if (tid < 9) {
        float dot = 0.f;
#pragma unroll
        for (int d = 0; d < 32; ++d) dot += kL[tid * 32 + d] * qL[d];
        int rm = tl * 9 + tid;
        int pm = rm >> 16, sm = rm & 65535;
        int dim = pm / 3 - 1, djm = pm - (pm / 3) * 3 - 1;
        int hm = sm >> 8, wm = sm & 255;
        bool mval = ((unsigned)(hm + dim) < 256u) && ((unsigned)(wm + djm) < 256u);
        wgtL[tid] = mval ? dot * 0.125f : 0.f;
    }
    __syncthreads();
    if (tid == 0) {
        float mx = wgtL[0];
#pragma unroll
        for (int s2 = 1; s2 < 9; ++s2) mx = fmaxf(mx, wgtL[s2]);
        float sum = 0.f;
#pragma unroll
        for (int s2 = 0; s2 < 9; ++s2) { wgtL[s2] = __expf(wgtL[s2] - mx); sum += wgtL[s2]; }
        wgtL[9] = 1.f / sum;
    }
    __syncthreads();
    if (tid < 32) {
        float acc = 0.f;
#pragma unroll
        for (int seg = 0; seg < 9; ++seg) acc += wgtL[seg] * vL[seg * 32 + tid];
        att[(size_t)b * 2097152 + (size_t)tl * 32 + tid] = __float2bfloat16(acc * wgtL[9]);
    }
}

// ---------------- K2: repack att (flat-identity planar bf16) -> tA (NHWC padded) ---
__global__ __launch_bounds__(256) void k_repack(
    const bf16* __restrict__ att, bf16* __restrict__ tA)
{
    int idx = blockIdx.x * 256 + threadIdx.x;   // [0, B*S*4)
    int icg = idx & 3;
    int ps  = idx >> 2;
    int b = ps >> 16;
    int s = ps & 65535;
    const bf16* src = att + (size_t)b * (32 * S_) + icg * 8 * S_ + s;
    short8 v;
#pragma unroll
    for (int j = 0; j < 8; ++j)
        v[j] = *reinterpret_cast<const short*>(src + (size_t)j * S_);
    int row = (s >> 8) + 1, colp = (s & 255) + 1;
    *reinterpret_cast<short8*>(tA + ((size_t)((b * PR + row) * PWN + colp)) * 32 + icg * 8) = v;
}

// ---------------- K4: 3x3 conv + ReLU via MFMA, one-shot LDS staging ----------------
template<int IC, int OC, bool NCHW_OUT>
__global__ __launch_bounds__(256) void k_conv3s(
    const bf16* __restrict__ in,    // NHWC bf16 padded [B][PR][PWN][IC]
    const bf16* __restrict__ apk,
    const float* __restrict__ bs,
    void* __restrict__ outv)
{
    constexpr int G    = IC / 8;
    constexpr int M    = OC / 32;
    constexpr int KPT  = IC / 16;
    constexpr int NK   = 9 * KPT;
    constexpr int NT   = 2;
    constexpr int ROWP = 66;
    constexpr int ROWG = ROWP * G;
    constexpr int TOTG = 6 * ROWG;

    __shared__ uint4 smem[TOTG];

    int wg   = blockIdx.x;
    int orig = (wg & 7) * 128 + (wg >> 3);
    int b   = orig >> 8;
    int rem = orig & 255;
    int h0  = (rem >> 2) << 2;
    int w0  = (rem & 3) * 64;

    int tid = threadIdx.x;

    {
        const uint4* src = reinterpret_cast<const uint4*>(in);
#pragma unroll
        for (int i = 0; i < (TOTG + 255) / 256; ++i) {
            int idx = tid + i * 256;
            if (idx < TOTG) {
                int dr = idx / ROWG;
                int r2 = idx - dr * ROWG;
                uint4 v = src[((size_t)(b * PR + h0 + dr) * PWN + w0) * G + r2];
                int px = r2 >> ((G == 4) ? 2 : 3);
                int sw = (G == 4) ? ((px ^ (px >> 2)) & 3) : (px & 7);
                smem[dr * ROWG + (r2 & ~(G - 1)) + ((r2 ^ sw) & (G - 1))] = v;
            }
        }
    }
    __syncthreads();

    int lane = tid & 63;
    int wid  = tid >> 6;
    int col  = lane & 31, q = lane >> 5;
    int h    = h0 + wid;

    const short8* apkv = reinterpret_cast<const short8*>(apk);

    f32x16 acc[NT][M];
#pragma unroll
    for (int nt = 0; nt < NT; ++nt)
#pragma unroll
        for (int mt = 0; mt < M; ++mt) acc[nt][mt] = (f32x16){};

#pragma unroll
    for (int tap = 0; tap < 9; ++tap) {
        int dr = tap / 3 + wid;
        int dj = tap % 3;
#pragma unroll
        for (int icq = 0; icq < KPT; ++icq) {
            short8 bfr[NT];
#pragma unroll
            for (int nt = 0; nt < NT; ++nt) {
                int px = nt * 32 + col + dj;
                int sw = (G == 4) ? ((px ^ (px >> 2)) & 3) : (px & 7);
                bfr[nt] = *reinterpret_cast<const short8*>(
                    &smem[dr * ROWG + px * G + ((icq * 2 + q) ^ sw)]);
            }
#pragma unroll
            for (int mt = 0; mt < M; ++mt) {
                short8 afr = apkv[(mt * NK + tap * KPT + icq) * 64 + lane];
#pragma unroll
                for (int nt = 0; nt < NT; ++nt)
                    acc[nt][mt] = __builtin_amdgcn_mfma_f32_32x32x16_bf16(
                        afr, bfr[nt], acc[nt][mt], 0, 0, 0);
            }
        }
    }

#pragma unroll
    for (int nt = 0; nt < NT; ++nt) {
        int wout = w0 + nt * 32 + col;
#pragma unroll
        for (int mt = 0; mt < M; ++mt) {
            if (NCHW_OUT) {
                float* out = (float*)outv;
#pragma unroll
                for (int r = 0; r < 16; ++r) {
                    int oc = mt * 32 + (r & 3) + 8 * (r >> 2) + 4 * q;
                    out[(size_t)((b * OC + oc) * H_ + h) * W_ + wout] =
                        fmaxf(acc[nt][mt][r] + bs[oc], 0.f);
                }
            } else {
                bf16* out = (bf16*)outv;
                size_t base = (size_t)((b * PR + h + 1) * PWN + wout + 1) * OC + mt * 32 + 4 * q;
#pragma unroll
                for (int g4 = 0; g4 < 4; ++g4) {
                    short4_t sv;
#pragma unroll
                    for (int r4 = 0; r4 < 4; ++r4) {
                        int oc = mt * 32 + 8 * g4 + 4 * q + r4;
                        bf16 hh = __float2bfloat16(fmaxf(acc[nt][mt][g4 * 4 + r4] + bs[oc], 0.f));
                        sv[r4] = *reinterpret_cast<short*>(&hh);
                    }
                    *reinterpret_cast<short4_t*>(out + base + 8 * g4) = sv;
                }
            }
        }
    }
}

extern "C" void kernel_launch(void* const* d_in, const int* in_sizes, int n_in,
                              void* d_out, int out_size, void* d_ws, size_t ws_size,
                              hipStream_t stream)
{
    const float* x  = (const float*)d_in[0];
    const float* wk = (const float*)d_in[1];
    const float* bk = (const float*)d_in[2];
    const float* wv = (const float*)d_in[3];
    const float* bv = (const float*)d_in[4];
    const float* wq = (const float*)d_in[5];
    const float* bq = (const float*)d_in[6];
    const float* w1 = (const float*)d_in[7];
    const float* b1 = (const float*)d_in[8];
    const float* w2 = (const float*)d_in[9];
    const float* b2 = (const float*)d_in[10];
    const float* w3 = (const float*)d_in[11];
    const float* b3 = (const float*)d_in[12];
    float* out = (float*)d_out;
    char* ws = (char*)d_ws;

    // ---- workspace layout (~104 MB) ----
    bf16* xqs  = (bf16*)(ws);                 // 16,777,216
    bf16* tA   = (bf16*)(ws + 16777216);      // 17,436,672
    bf16* t1   = (bf16*)(ws + 34213888);      // 17,436,672
    bf16* t2   = (bf16*)(ws + 51650560);      // 34,873,344
    bf16* apk0 = (bf16*)(ws + 86523904);      // 38,912
    bf16* apk1 = (bf16*)(ws + 86562816);      // 18,432
    bf16* apk2 = (bf16*)(ws + 86581248);      // 36,864
    bf16* apk3 = (bf16*)(ws + 86618112);      // 36,864  (end 86,654,976)
    bf16* xb16 = (bf16*)(ws + 86654976);      // (4*66056+512)*64 = 16,975,872 B
    bf16* attB = (bf16*)d_out;                // attention out scratch

    static bool attr_set = false;
    if (!attr_set) {
        hipFuncSetAttribute(reinterpret_cast<const void*>(k_fused),
                            hipFuncAttributeMaxDynamicSharedMemorySize, 110976);
        attr_set = true;
    }

    k_qp<<<2605, 256, 0, stream>>>(x, wk, wv, wq, bq, w1, w2, w3,
                                   apk0, apk1, apk2, apk3,
                                   (uint4*)tA, (uint4*)t1, (uint4*)t2,
                                   xqs, xb16);

    k_fused<<<512, 1024, 110976, stream>>>(xb16, apk0, bk, bv, xqs, attB);

    k_strad<<<1024, 320, 0, stream>>>(xb16, wk, bk, wv, bv, xqs, attB);

    k_repack<<<4096, 256, 0, stream>>>(attB, tA);

    k_conv3s<32, 32, false><<<1024, 256, 0, stream>>>(tA, apk1, b1, (void*)t1);
    k_conv3s<32, 64, false><<<1024, 256, 0, stream>>>(t1, apk2, b2, (void*)t2);
    k_conv3s<64, 32, true ><<<1024, 256, 0, stream>>>(t2, apk3, b3, (void*)out);
}

// Round 18
// 153.047 us; speedup vs baseline: 1.0576x; 1.0576x over previous
//
#include <hip/hip_runtime.h>
#include <hip/hip_bf16.h>

#define B_ 4
#define C_ 32
#define H_ 256
#define W_ 256
#define S_ 65536      // H*W
#define NP_ 9
#define OC_ 288       // C_*NP_
#define PR 258        // padded rows
#define PWN 264       // padded width stride (NHWC)
#define XGUARD 260    // guard pixels on each side of xb16
#define XSTRIDE 66056 // per-batch px stride of xb16 (260+65536+260)

using bf16 = __hip_bfloat16;
typedef __attribute__((ext_vector_type(8)))  short  short8;
typedef __attribute__((ext_vector_type(4)))  short  short4_t;
typedef __attribute__((ext_vector_type(2)))  short  short2_t;
typedef __attribute__((ext_vector_type(16))) float  f32x16;

__device__ __forceinline__ float b2f(short s) {
    return __uint_as_float(((unsigned)(unsigned short)s) << 16);
}

// ---------------- prep bodies ----------------
template<int IC, int OC>
__device__ __forceinline__ void prepA_body(int fid, const float* __restrict__ w,
                                           bf16* __restrict__ apk)
{
    constexpr int NK = 9 * IC / 16;
    int tile = fid >> 9;
    int l = (fid >> 3) & 63;
    int j = fid & 7;
    int mt = tile / NK;
    int ks = tile - mt * NK;
    int q = l >> 5;
    int oc = mt * 32 + (l & 31);
    int k = ks * 16 + q * 8 + j;
    int tap = k / IC;
    int ic = k - tap * IC;
    apk[fid] = __float2bfloat16(w[((oc * IC + ic) * 3 + tap / 3) * 3 + tap % 3]);
}

template<int G>
__device__ __forceinline__ void zerob_body(int b, int p, uint4* __restrict__ buf)
{
    int gran;
    if (p < 2 * PWN * G) {
        int row = (p < PWN * G) ? 0 : 257;
        int rem = p % (PWN * G);
        gran = row * PWN * G + rem;
    } else {
        int p2 = p - 2 * PWN * G;
        int col = (p2 < 256 * G) ? 0 : 257;
        int rem = p2 % (256 * G);
        int r = rem / G + 1;
        int icg = rem - (rem / G) * G;
        gran = (r * PWN + col) * G + icg;
    }
    buf[(size_t)b * PR * PWN * G + gran] = uint4{0, 0, 0, 0};
}

__device__ __forceinline__ void prep_body(
    int idx,
    const float* __restrict__ wk, const float* __restrict__ wv,
    const float* __restrict__ wq,
    const float* __restrict__ w1, const float* __restrict__ w2,
    const float* __restrict__ w3,
    bf16* __restrict__ apk0, bf16* __restrict__ apk1,
    bf16* __restrict__ apk2, bf16* __restrict__ apk3,
    uint4* __restrict__ tA, uint4* __restrict__ t1, uint4* __restrict__ t2,
    uint4* __restrict__ xb16)
{
    if (idx < 19456) {
        int j    = idx & 7;
        int lane = (idx >> 3) & 63;
        int ks   = (idx >> 9) & 1;
        int mt   = idx >> 10;
        int oc = lane & 31;
        int ic = ks * 16 + (lane >> 5) * 8 + j;
        const float* w; int ocg;
        if (mt < 9)       { w = wk; ocg = mt * 32 + oc; }
        else if (mt < 18) { w = wv; ocg = (mt - 9) * 32 + oc; }
        else              { w = wq; ocg = oc; }
        apk0[idx] = __float2bfloat16(w[ocg * C_ + ic]);
    } else if (idx < 28672) {
        prepA_body<32, 32>(idx - 19456, w1, apk1);
    } else if (idx < 47104) {
        prepA_body<32, 64>(idx - 28672, w2, apk2);
    } else if (idx < 65536) {
        prepA_body<64, 32>(idx - 47104, w3, apk3);
    } else if (idx < 82176) {
        int i5 = idx - 65536;
        zerob_body<4>(i5 / 4160, i5 % 4160, tA);
    } else if (idx < 98816) {
        int i6 = idx - 82176;
        zerob_body<4>(i6 / 4160, i6 % 4160, t1);
    } else if (idx < 132096) {
        int i7 = idx - 98816;
        zerob_body<8>(i7 / 8320, i7 % 8320, t2);
    } else if (idx < 142464) {
        // zero xb16 guard bands: head [-260,0), tail [65536,65796) per batch + slack
        int i8 = idx - 132096;           // [0, 10368)
        size_t off;
        if (i8 < 8320) {
            int b = i8 / 2080, r = i8 - b * 2080;
            if (r < 1040) off = (size_t)b * (XSTRIDE * 4) + r;
            else          off = ((size_t)b * XSTRIDE + XGUARD + 65536) * 4 + (r - 1040);
        } else {
            off = (size_t)(4 * XSTRIDE) * 4 + (i8 - 8320);
        }
        xb16[off] = uint4{0, 0, 0, 0};
    }
}

// ---------------- K_qp: merged {k_prep} + {1x1 Q-conv + x->bf16 NHWC repack} -------
__global__ __launch_bounds__(256) void k_qp(
    const float* __restrict__ x,
    const float* __restrict__ wk, const float* __restrict__ wv,
    const float* __restrict__ wq, const float* __restrict__ bq,
    const float* __restrict__ w1, const float* __restrict__ w2,
    const float* __restrict__ w3,
    bf16* __restrict__ apk0, bf16* __restrict__ apk1,
    bf16* __restrict__ apk2, bf16* __restrict__ apk3,
    uint4* __restrict__ tA, uint4* __restrict__ t1, uint4* __restrict__ t2,
    bf16* __restrict__ xqs, bf16* __restrict__ xb16)
{
    __shared__ bf16 lbuf[32][140];
    int tid = threadIdx.x;

    if (blockIdx.x >= 2048) {
        prep_body((blockIdx.x - 2048) * 256 + tid, wk, wv, wq, w1, w2, w3,
                  apk0, apk1, apk2, apk3, tA, t1, t2, (uint4*)xb16);
        return;
    }

    int bh  = blockIdx.x >> 9;          // batch 0..3
    int blk = blockIdx.x & 511;
    int pixw0 = blk << 7;
    int wvi  = tid >> 6;
    int lane = tid & 63;
    int col  = lane & 31, q = lane >> 5;
    int pix  = pixw0 + wvi * 32 + col;

    const float* xb = x + (size_t)bh * (C_ * S_);

    short8 bfrag[2];
#pragma unroll
    for (int kk = 0; kk < 2; ++kk)
#pragma unroll
        for (int j = 0; j < 8; ++j) {
            bf16 h = __float2bfloat16(xb[(size_t)(kk * 16 + q * 8 + j) * S_ + pix]);
            bfrag[kk][j] = *reinterpret_cast<short*>(&h);
        }

    // x -> bf16 NHWC: granule g = ic/8 = kk*2+q
    {
        bf16* xr = xb16 + ((size_t)bh * XSTRIDE + XGUARD + pix) * 32;
        *reinterpret_cast<short8*>(xr + (q << 3))       = bfrag[0];
        *reinterpret_cast<short8*>(xr + ((2 + q) << 3)) = bfrag[1];
    }

    // self-packed q-weight fragments (same layout k_prep would emit for mt=18)
    short8 wfrag[2];
#pragma unroll
    for (int kk = 0; kk < 2; ++kk)
#pragma unroll
        for (int j = 0; j < 8; ++j) {
            bf16 h = __float2bfloat16(wq[col * C_ + kk * 16 + q * 8 + j]);
            wfrag[kk][j] = *reinterpret_cast<short*>(&h);
        }

    f32x16 acc = {};
    acc = __builtin_amdgcn_mfma_f32_32x32x16_bf16(bfrag[0], wfrag[0], acc, 0, 0, 0);
    acc = __builtin_amdgcn_mfma_f32_32x32x16_bf16(bfrag[1], wfrag[1], acc, 0, 0, 0);
    float bbv = bq[col];
#pragma unroll
    for (int g4 = 0; g4 < 4; ++g4) {
        short4_t sv;
#pragma unroll
        for (int j = 0; j < 4; ++j) {
            bf16 hb = __float2bfloat16(acc[g4 * 4 + j] + bbv);
            sv[j] = *reinterpret_cast<short*>(&hb);
        }
        *reinterpret_cast<short4_t*>(&lbuf[col][wvi * 32 + 8 * g4 + 4 * q]) = sv;
    }
    __syncthreads();
    // swizzled q store: row (ch*2048 + tb) holds px [tb*32, tb*32+32) of plane ch
    int ch0 = tid >> 4, chk = tid & 15, ch1 = ch0 + 16;
    short8 v0 = *reinterpret_cast<const short8*>(&lbuf[ch0][chk * 8]);
    short8 v1 = *reinterpret_cast<const short8*>(&lbuf[ch1][chk * 8]);
    int tb = (pixw0 >> 5) + (chk >> 2);
    int G2 = chk & 3;
    bf16* qb = xqs + (size_t)bh * (32 * S_);
    short4_t lo0 = {v0[0], v0[1], v0[2], v0[3]}, hi0 = {v0[4], v0[5], v0[6], v0[7]};
    short4_t lo1 = {v1[0], v1[1], v1[2], v1[3]}, hi1 = {v1[4], v1[5], v1[6], v1[7]};
    *reinterpret_cast<short4_t*>(qb + (ch0 * 2048 + tb) * 32 + G2 * 4)      = lo0;
    *reinterpret_cast<short4_t*>(qb + (ch0 * 2048 + tb) * 32 + 16 + G2 * 4) = hi0;
    *reinterpret_cast<short4_t*>(qb + (ch1 * 2048 + tb) * 32 + G2 * 4)      = lo1;
    *reinterpret_cast<short4_t*>(qb + (ch1 * 2048 + tb) * 32 + 16 + G2 * 4) = hi1;
}

// ---------------- fused K/V-conv + attention (ping-pong LDS, 1 barrier/tap) --------
// Block = (batch, 512-px chunk), 1024 threads, 111KB dyn LDS, 1 block/CU.
// x frags read from xb16 global (L2-resident). kvB+scL double-buffered:
// iteration p = { P2(p) reads buf[p&1] || P1(p+1) writes buf[(p+1)&1] } then ONE
// barrier. q fragments prefetched one tap ahead. (R16 exact — best measured.)

#define Q_LOAD(T, PN, QA, QB)                                                         \
{                                                                                     \
    int Tg = tgbase + (T);                                                            \
    if (Tg < 2048) {                                                                  \
        int plane_base_n = (((PN) << 5) + col) << 16;                                 \
        unsigned n = (unsigned)plane_base_n + ((unsigned)Tg << 5);                    \
        unsigned tl = n / 288u;                                                       \
        const bf16* qp = xqb + ((size_t)tl << 5) + (q << 4);                          \
        QA = *reinterpret_cast<const short8*>(qp);                                    \
        QB = *reinterpret_cast<const short8*>(qp + 8);                                \
    }                                                                                 \
}

#define DO_TILE(T, SQ, QAv, QBv, PP)                                                  \
{                                                                                     \
    int Tg = tgbase + (T);                                                            \
    if (Tg < 2048) {                                                                  \
        short8 qA = QAv;                                                              \
        short8 qB = QBv;                                                              \
        const bf16* xp = xbb + (size_t)(XGUARD + (Tg << 5) + shf + col) * 32;         \
        short8 fa = *reinterpret_cast<const short8*>(xp + (q << 3));                  \
        short8 fb = *reinterpret_cast<const short8*>(xp + ((2 + q) << 3));            \
        bool hbad  = ((((T) << 5) < hb_lo) || (((T) << 5) >= hb_hi));                 \
        bool tb_lo = (dj == -1) && ((Tg & 7) == 0);                                   \
        bool tb_hi = (dj == 1) && ((Tg & 7) == 7);                                    \
        if (tb_lo && q == 0) qA[0] = 0;                                               \
        if (tb_hi && q == 1) qB[7] = 0;                                               \
        f32x16 ka = {bK, bK, bK, bK, bK, bK, bK, bK, bK, bK, bK, bK, bK, bK, bK, bK}; \
        ka = __builtin_amdgcn_mfma_f32_32x32x16_bf16(fa, apkv[((PP) * 2 + 0) * 64 + lane], ka, 0, 0, 0); \
        ka = __builtin_amdgcn_mfma_f32_32x32x16_bf16(fb, apkv[((PP) * 2 + 1) * 64 + lane], ka, 0, 0, 0); \
        float dot = 0.f;                                                              \
        _Pragma("unroll")                                                             \
        for (int j3 = 0; j3 < 4; ++j3) {                                              \
            dot += ka[j3]      * b2f(qA[j3]);                                         \
            dot += ka[4 + j3]  * b2f(qA[4 + j3]);                                     \
            dot += ka[8 + j3]  * b2f(qB[j3]);                                         \
            dot += ka[12 + j3] * b2f(qB[4 + j3]);                                     \
        }                                                                             \
        if (hbad) dot = 0.f;                                                          \
        dot += __shfl_xor(dot, 32);                                                   \
        if (q == (SQ)) scW[(T) * 32 + col] = dot;                                     \
        f32x16 vh = {bV, bV, bV, bV, bV, bV, bV, bV, bV, bV, bV, bV, bV, bV, bV, bV}; \
        vh = __builtin_amdgcn_mfma_f32_32x32x16_bf16(fa, apkv[((9 + (PP)) * 2 + 0) * 64 + lane], vh, 0, 0, 0); \
        vh = __builtin_amdgcn_mfma_f32_32x32x16_bf16(fb, apkv[((9 + (PP)) * 2 + 1) * 64 + lane], vh, 0, 0, 0); \
        _Pragma("unroll")                                                             \
        for (int G2 = 0; G2 < 4; ++G2) {                                              \
            short4_t sv;                                                              \
            _Pragma("unroll")                                                         \
            for (int j3 = 0; j3 < 4; ++j3) {                                          \
                float val = hbad ? 0.f : vh[G2 * 4 + j3];                             \
                bf16 hcv = __float2bfloat16(val);                                     \
                sv[j3] = *reinterpret_cast<short*>(&hcv);                             \
            }                                                                         \
            if (G2 == 0 && tb_lo && q == 0) sv[0] = 0;                                \
            if (G2 == 3 && tb_hi && q == 1) sv[3] = 0;                                \
            *reinterpret_cast<short4_t*>(kvW + col * 1616 +                           \
                ((((T) << 2) + (G2 ^ xcol)) << 4) + q * 8) = sv;                      \
        }                                                                             \
    }                                                                                 \
}

#define P1_SETUP(PP)                                                                  \
    int di = (PP) / 3 - 1, dj = (PP) - ((PP) / 3) * 3 - 1;                            \
    int shf = di * 256 + dj;                                                          \
    int hb_lo = (di == -1) ? (256 - s0) : (-0x40000000);                              \
    int hb_hi = (di == 1) ? (65280 - s0) : 0x40000000;                                \
    float bK = bk[(PP) * 32 + col];                                                   \
    float bV = bv[(PP) * 32 + col];

__global__ __launch_bounds__(1024, 4) void k_fused(
    const bf16* __restrict__ xb16,      // [4][XSTRIDE][32] bf16 NHWC (+guards)
    const bf16* __restrict__ apk,       // packed weights [19][2][64][8]
    const float* __restrict__ bk, const float* __restrict__ bv,
    const bf16* __restrict__ xqs,       // [4][65536 rows][32] swizzled rows
    bf16* __restrict__ att)             // [4][2097152] flat bf16
{
    extern __shared__ char smem_raw[];
    char*  kvB0 = smem_raw;                                     // 51712
    char*  kvB1 = smem_raw + 51712;                             // 51712
    float* scL0 = reinterpret_cast<float*>(smem_raw + 103424);  // 3200
    float* scL1 = reinterpret_cast<float*>(smem_raw + 106624);  // 3200
    unsigned short* scM = reinterpret_cast<unsigned short*>(smem_raw + 109824); // 1152
    // total 110,976

    int bb = blockIdx.x >> 7;
    int s0 = (blockIdx.x & 127) << 9;
    int tgbase = s0 >> 5;

    int tid  = threadIdx.x;
    int lane = tid & 63;
    int wv   = tid >> 6;                // 0..15
    int col  = lane & 31;
    int q    = lane >> 5;
    int xcol = (col >> 3) & 3;

    size_t qbase = ((size_t)bb << 21);
    const bf16* xqb = xqs + qbase;
    const bf16* xbb = xb16 + (size_t)bb * XSTRIDE * 32;
    const short8* apkv = reinterpret_cast<const short8*>(apk);

    // ---- strip validity + seg-mask table (once per block) ----
    if (tid < 576) {
        int krow = tid >= 288;
        int i2 = tid - (krow ? 288 : 0);
        int pp = i2 >> 5, dpc = i2 & 31;
        int plane_base_r = ((pp << 5) + dpc) << 16;
        unsigned tl = ((unsigned)(plane_base_r + s0 + 287)) / 288u + (unsigned)krow;
        int sk0 = (int)(tl * 288u) - plane_base_r;
        unsigned m = 0;
        if (sk0 < s0 + 512 && sk0 <= 65248) {
            m = 0x8000u;
#pragma unroll
            for (int seg = 0; seg < 9; ++seg) {
                int rm = (int)tl * 9 + seg;
                int pm = rm >> 16, sm = rm & 65535;
                int dim = pm / 3 - 1, djm = pm - (pm / 3) * 3 - 1;
                int hm = sm >> 8, wm = sm & 255;
                bool mval = ((unsigned)(hm + dim) < 256u) && ((unsigned)(wm + djm) < 256u);
                m |= (mval ? 1u : 0u) << seg;
            }
        }
        scM[tid] = (unsigned short)m;
    }

    // prologue: q for tap 0, then P1(0) into buf0, prefetch q for tap 1
    short8 qA0, qB0, qA1, qB1;
    Q_LOAD(wv, 0, qA0, qB0)
    if (wv < 9) { Q_LOAD(wv + 16, 0, qA1, qB1) }
    {
        P1_SETUP(0)
        char*  kvW = kvB0;
        float* scW = scL0;
        DO_TILE(wv, 0, qA0, qB0, 0)
        if (wv < 9) { DO_TILE(wv + 16, 1, qA1, qB1, 0) }
        Q_LOAD(wv, 1, qA0, qB0)
        if (wv < 9) { Q_LOAD(wv + 16, 1, qA1, qB1) }
    }
    __syncthreads();

    // P2 thread map: tid<512, 8 threads per (plane, krow)
    int grp  = tid >> 3, sub = tid & 7;
    int dp   = grp & 31;
    int krow = (grp >> 5) & 1;
    int hh   = sub >> 1;
    int sh   = sub & 1;
    bool athr = tid < 512;
    int swz = (dp >> 3) & 3;

#pragma unroll 1
    for (int p = 0; p < 9; ++p) {
        const char*  kvR = (p & 1) ? kvB1 : kvB0;
        const float* scR = (p & 1) ? scL1 : scL0;

        // ---- P2(p): softmax from scR/scM + PV from kvR ----
        if (athr) {
            unsigned mflags = scM[krow * 288 + p * 32 + dp];
            if (mflags & 0x8000u) {
                int plane_base_r = ((p << 5) + dp) << 16;
                unsigned tl = ((unsigned)(plane_base_r + s0 + 287)) / 288u + (unsigned)krow;
                int sk0 = (int)(tl * 288u) - plane_base_r;
                int t0 = (sk0 - s0) >> 5;
                float sc[9];
#pragma unroll
                for (int seg = 0; seg < 9; ++seg)
                    sc[seg] = ((mflags >> seg) & 1u) ? scR[(t0 + seg) * 32 + dp] * 0.125f : 0.f;
                float mx = sc[0];
#pragma unroll
                for (int s2 = 1; s2 < 9; ++s2) mx = fmaxf(mx, sc[s2]);
                float wgt[9];
                float sum = 0.f;
#pragma unroll
                for (int s2 = 0; s2 < 9; ++s2) { wgt[s2] = __expf(sc[s2] - mx); sum += wgt[s2]; }
                float inv_ = 1.f / sum;

                float oacc[4] = {0.f, 0.f, 0.f, 0.f};
#pragma unroll
                for (int seg = 0; seg < 9; ++seg) {
                    short4_t vg = *reinterpret_cast<const short4_t*>(
                        kvR + dp * 1616 + ((((t0 + seg) << 2) + (hh ^ swz)) << 4) + sh * 8);
                    float w_ = wgt[seg];
#pragma unroll
                    for (int j = 0; j < 4; ++j) oacc[j] += w_ * b2f(vg[j]);
                }
                short4_t sv;
#pragma unroll
                for (int j = 0; j < 4; ++j) {
                    bf16 h = __float2bfloat16(oacc[j] * inv_);
                    sv[j] = *reinterpret_cast<short*>(&h);
                }
                *reinterpret_cast<short4_t*>(att + qbase + ((size_t)tl << 5) + hh * 8 + sh * 4) = sv;
            }
        }

        // ---- P1(p+1): conv into the other buffer (no barrier needed before) ----
        if (p < 8) {
            P1_SETUP(p + 1)
            char*  kvW = ((p + 1) & 1) ? kvB1 : kvB0;
            float* scW = ((p + 1) & 1) ? scL1 : scL0;
            DO_TILE(wv, 0, qA0, qB0, p + 1)
            if (wv < 9) { DO_TILE(wv + 16, 1, qA1, qB1, p + 1) }
            if (p < 7) {
                Q_LOAD(wv, p + 2, qA0, qB0)
                if (wv < 9) { Q_LOAD(wv + 16, p + 2, qA1, qB1) }
            }
        }
        __syncthreads();
    }
}

// ---------------- straddler rows: strip crosses a plane boundary ------------------
__global__ __launch_bounds__(320) void k_strad(
    const bf16* __restrict__ xb16,
    const float* __restrict__ wk, const float* __restrict__ bk,
    const float* __restrict__ wv, const float* __restrict__ bv,
    const bf16* __restrict__ xqs, bf16* __restrict__ att)
{
    __shared__ float kL[288], vL[288], qL[32], wgtL[10];
    int e = blockIdx.x;
    int b = e >> 8, i = e & 255;
    int g = i >> 3, u = i & 7;
    int tl = g * 2048 + (((2040 + u) * 1593) & 2047);
    int tid = threadIdx.x;

    if (tid < 288) {
        int f  = tl * 288 + tid;
        int cp = f >> 16;
        int sp = f & 65535;
        int tap = cp >> 5;
        int di = tap / 3 - 1, dj = tap - (tap / 3) * 3 - 1;
        int h = sp >> 8, w = sp & 255;
        bool valid = ((unsigned)(h + di) < 256u) && ((unsigned)(w + dj) < 256u);
        float kv_ = 0.f, vv_ = 0.f;
        if (valid) {
            int sx = sp + di * 256 + dj;
            const bf16* xp = xb16 + ((size_t)b * XSTRIDE + XGUARD + sx) * 32;
            const float* wkp = wk + cp * 32;
            const float* wvp = wv + cp * 32;
            float ks = bk[cp], vs = bv[cp];
            short8 xg[4];
#pragma unroll
            for (int gg = 0; gg < 4; ++gg)
                xg[gg] = *reinterpret_cast<const short8*>(xp + gg * 8);
#pragma unroll
            for (int gg = 0; gg < 4; ++gg)
#pragma unroll
                for (int j = 0; j < 8; ++j) {
                    float xv_ = b2f(xg[gg][j]);
                    ks += wkp[gg * 8 + j] * xv_;
                    vs += wvp[gg * 8 + j] * xv_;
                }
            kv_ = ks; vv_ = vs;
        }
        kL[tid] = kv_; vL[tid] = vv_;
    }
    if (tid < 32) {
        // q-row tl element u=tid at swizzled pos(u)
        int pos = ((tid >> 2) & 1) * 16 + (tid >> 3) * 4 + (tid & 3);
        bf16 hv = xqs[(size_t)b * (32 * S_) + (size_t)tl * 32 + pos];
        qL[tid] = b2f(*reinterpret_cast<short*>(&hv));
    }
    __syncthreads();
    if (tid < 9) {
        float dot = 0.f;
#pragma unroll
        for (int d = 0; d < 32; ++d) dot += kL[tid * 32 + d] * qL[d];
        int rm = tl * 9 + tid;
        int pm = rm >> 16, sm = rm & 65535;
        int dim = pm / 3 - 1, djm = pm - (pm / 3) * 3 - 1;
        int hm = sm >> 8, wm = sm & 255;
        bool mval = ((unsigned)(hm + dim) < 256u) && ((unsigned)(wm + djm) < 256u);
        wgtL[tid] = mval ? dot * 0.125f : 0.f;
    }
    __syncthreads();
    if (tid == 0) {
        float mx = wgtL[0];
#pragma unroll
        for (int s2 = 1; s2 < 9; ++s2) mx = fmaxf(mx, wgtL[s2]);
        float sum = 0.f;
#pragma unroll
        for (int s2 = 0; s2 < 9; ++s2) { wgtL[s2] = __expf(wgtL[s2] - mx); sum += wgtL[s2]; }
        wgtL[9] = 1.f / sum;
    }
    __syncthreads();
    if (tid < 32) {
        float acc = 0.f;
#pragma unroll
        for (int seg = 0; seg < 9; ++seg) acc += wgtL[seg] * vL[seg * 32 + tid];
        att[(size_t)b * 2097152 + (size_t)tl * 32 + tid] = __float2bfloat16(acc * wgtL[9]);
    }
}

// ---------------- K2: repack att (flat-identity planar bf16) -> tA (NHWC padded) ---
__global__ __launch_bounds__(256) void k_repack(
    const bf16* __restrict__ att, bf16* __restrict__ tA)
{
    int idx = blockIdx.x * 256 + threadIdx.x;   // [0, B*S*4)
    int icg = idx & 3;
    int ps  = idx >> 2;
    int b = ps >> 16;
    int s = ps & 65535;
    const bf16* src = att + (size_t)b * (32 * S_) + icg * 8 * S_ + s;
    short8 v;
#pragma unroll
    for (int j = 0; j < 8; ++j)
        v[j] = *reinterpret_cast<const short*>(src + (size_t)j * S_);
    int row = (s >> 8) + 1, colp = (s & 255) + 1;
    *reinterpret_cast<short8*>(tA + ((size_t)((b * PR + row) * PWN + colp)) * 32 + icg * 8) = v;
}

// ---------------- K4: 3x3 conv + ReLU via MFMA, one-shot LDS staging ----------------
template<int IC, int OC, bool NCHW_OUT>
__global__ __launch_bounds__(256) void k_conv3s(
    const bf16* __restrict__ in,    // NHWC bf16 padded [B][PR][PWN][IC]
    const bf16* __restrict__ apk,
    const float* __restrict__ bs,
    void* __restrict__ outv)
{
    constexpr int G    = IC / 8;
    constexpr int M    = OC / 32;
    constexpr int KPT  = IC / 16;
    constexpr int NK   = 9 * KPT;
    constexpr int NT   = 2;
    constexpr int ROWP = 66;
    constexpr int ROWG = ROWP * G;
    constexpr int TOTG = 6 * ROWG;

    __shared__ uint4 smem[TOTG];

    int wg   = blockIdx.x;
    int orig = (wg & 7) * 128 + (wg >> 3);
    int b   = orig >> 8;
    int rem = orig & 255;
    int h0  = (rem >> 2) << 2;
    int w0  = (rem & 3) * 64;

    int tid = threadIdx.x;

    {
        const uint4* src = reinterpret_cast<const uint4*>(in);
#pragma unroll
        for (int i = 0; i < (TOTG + 255) / 256; ++i) {
            int idx = tid + i * 256;
            if (idx < TOTG) {
                int dr = idx / ROWG;
                int r2 = idx - dr * ROWG;
                uint4 v = src[((size_t)(b * PR + h0 + dr) * PWN + w0) * G + r2];
                int px = r2 >> ((G == 4) ? 2 : 3);
                int sw = (G == 4) ? ((px ^ (px >> 2)) & 3) : (px & 7);
                smem[dr * ROWG + (r2 & ~(G - 1)) + ((r2 ^ sw) & (G - 1))] = v;
            }
        }
    }
    __syncthreads();

    int lane = tid & 63;
    int wid  = tid >> 6;
    int col  = lane & 31, q = lane >> 5;
    int h    = h0 + wid;

    const short8* apkv = reinterpret_cast<const short8*>(apk);

    f32x16 acc[NT][M];
#pragma unroll
    for (int nt = 0; nt < NT; ++nt)
#pragma unroll
        for (int mt = 0; mt < M; ++mt) acc[nt][mt] = (f32x16){};

#pragma unroll
    for (int tap = 0; tap < 9; ++tap) {
        int dr = tap / 3 + wid;
        int dj = tap % 3;
#pragma unroll
        for (int icq = 0; icq < KPT; ++icq) {
            short8 bfr[NT];
#pragma unroll
            for (int nt = 0; nt < NT; ++nt) {
                int px = nt * 32 + col + dj;
                int sw = (G == 4) ? ((px ^ (px >> 2)) & 3) : (px & 7);
                bfr[nt] = *reinterpret_cast<const short8*>(
                    &smem[dr * ROWG + px * G + ((icq * 2 + q) ^ sw)]);
            }
#pragma unroll
            for (int mt = 0; mt < M; ++mt) {
                short8 afr = apkv[(mt * NK + tap * KPT + icq) * 64 + lane];
#pragma unroll
                for (int nt = 0; nt < NT; ++nt)
                    acc[nt][mt] = __builtin_amdgcn_mfma_f32_32x32x16_bf16(
                        afr, bfr[nt], acc[nt][mt], 0, 0, 0);
            }
        }
    }

#pragma unroll
    for (int nt = 0; nt < NT; ++nt) {
        int wout = w0 + nt * 32 + col;
#pragma unroll
        for (int mt = 0; mt < M; ++mt) {
            if (NCHW_OUT) {
                float* out = (float*)outv;
#pragma unroll
                for (int r = 0; r < 16; ++r) {
                    int oc = mt * 32 + (r & 3) + 8 * (r >> 2) + 4 * q;
                    out[(size_t)((b * OC + oc) * H_ + h) * W_ + wout] =
                        fmaxf(acc[nt][mt][r] + bs[oc], 0.f);
                }
            } else {
                bf16* out = (bf16*)outv;
                size_t base = (size_t)((b * PR + h + 1) * PWN + wout + 1) * OC + mt * 32 + 4 * q;
#pragma unroll
                for (int g4 = 0; g4 < 4; ++g4) {
                    short4_t sv;
#pragma unroll
                    for (int r4 = 0; r4 < 4; ++r4) {
                        int oc = mt * 32 + 8 * g4 + 4 * q + r4;
                        bf16 hh = __float2bfloat16(fmaxf(acc[nt][mt][g4 * 4 + r4] + bs[oc], 0.f));
                        sv[r4] = *reinterpret_cast<short*>(&hh);
                    }
                    *reinterpret_cast<short4_t*>(out + base + 8 * g4) = sv;
                }
            }
        }
    }
}

extern "C" void kernel_launch(void* const* d_in, const int* in_sizes, int n_in,
                              void* d_out, int out_size, void* d_ws, size_t ws_size,
                              hipStream_t stream)
{
    const float* x  = (const float*)d_in[0];
    const float* wk = (const float*)d_in[1];
    const float* bk = (const float*)d_in[2];
    const float* wv = (const float*)d_in[3];
    const float* bv = (const float*)d_in[4];
    const float* wq = (const float*)d_in[5];
    const float* bq = (const float*)d_in[6];
    const float* w1 = (const float*)d_in[7];
    const float* b1 = (const float*)d_in[8];
    const float* w2 = (const float*)d_in[9];
    const float* b2 = (const float*)d_in[10];
    const float* w3 = (const float*)d_in[11];
    const float* b3 = (const float*)d_in[12];
    float* out = (float*)d_out;
    char* ws = (char*)d_ws;

    // ---- workspace layout (~104 MB) ----
    bf16* xqs  = (bf16*)(ws);                 // 16,777,216
    bf16* tA   = (bf16*)(ws + 16777216);      // 17,436,672
    bf16* t1   = (bf16*)(ws + 34213888);      // 17,436,672
    bf16* t2   = (bf16*)(ws + 51650560);      // 34,873,344
    bf16* apk0 = (bf16*)(ws + 86523904);      // 38,912
    bf16* apk1 = (bf16*)(ws + 86562816);      // 18,432
    bf16* apk2 = (bf16*)(ws + 86581248);      // 36,864
    bf16* apk3 = (bf16*)(ws + 86618112);      // 36,864  (end 86,654,976)
    bf16* xb16 = (bf16*)(ws + 86654976);      // (4*66056+512)*64 = 16,975,872 B
    bf16* attB = (bf16*)d_out;                // attention out scratch

    static bool attr_set = false;
    if (!attr_set) {
        hipFuncSetAttribute(reinterpret_cast<const void*>(k_fused),
                            hipFuncAttributeMaxDynamicSharedMemorySize, 110976);
        attr_set = true;
    }

    k_qp<<<2605, 256, 0, stream>>>(x, wk, wv, wq, bq, w1, w2, w3,
                                   apk0, apk1, apk2, apk3,
                                   (uint4*)tA, (uint4*)t1, (uint4*)t2,
                                   xqs, xb16);

    k_fused<<<512, 1024, 110976, stream>>>(xb16, apk0, bk, bv, xqs, attB);

    k_strad<<<1024, 320, 0, stream>>>(xb16, wk, bk, wv, bv, xqs, attB);

    k_repack<<<4096, 256, 0, stream>>>(attB, tA);

    k_conv3s<32, 32, false><<<1024, 256, 0, stream>>>(tA, apk1, b1, (void*)t1);
    k_conv3s<32, 64, false><<<1024, 256, 0, stream>>>(t1, apk2, b2, (void*)t2);
    k_conv3s<64, 32, true ><<<1024, 256, 0, stream>>>(t2, apk3, b3, (void*)out);
}